// Round 2
// baseline (1745.609 us; speedup 1.0000x reference)
//
#include <hip/hip_runtime.h>

// mLSTM block forward, MI355X gfx950.
// Round 2: resubmit of round-0 kernel (round 1 was a broker timeout, no signal).
// Only change: dropped unused xconv_f f32 buffer (-64MB ws, -64MB HBM writes).

typedef __bf16 bf16_t;
typedef bf16_t bf16x8 __attribute__((ext_vector_type(8)));
typedef bf16_t bf16x4 __attribute__((ext_vector_type(4)));
typedef float f32x4 __attribute__((ext_vector_type(4)));

#define B_ROWS 8192
#define DMODEL 1024
#define HDIM   2048

__device__ __forceinline__ void gload_lds16(const void* g, void* s) {
  __builtin_amdgcn_global_load_lds(
      (const __attribute__((address_space(1))) void*)g,
      (__attribute__((address_space(3))) void*)s, 16, 0, 0);
}

__device__ __forceinline__ float sigmoidf_(float x) { return 1.f / (1.f + __expf(-x)); }
__device__ __forceinline__ float siluf_(float x)    { return x / (1.f + __expf(-x)); }

// ---------------------------------------------------------------------------
// Transpose + convert: in f32 (R x C) -> out bf16 (C x R). Batched over z.
// R, C multiples of 64.
__global__ __launch_bounds__(256) void wtrans_kernel(
    const float* __restrict__ in, bf16_t* __restrict__ out, int R, int C) {
  const int z = blockIdx.z;
  in  += (size_t)z * R * C;
  out += (size_t)z * R * C;
  __shared__ float tile[64][65];
  const int t = threadIdx.x;
  const int r0 = blockIdx.y * 64, c0 = blockIdx.x * 64;
#pragma unroll
  for (int j = 0; j < 4; ++j) {
    const int r = j * 16 + (t >> 4);
    const int c = (t & 15) * 4;
    float4 v = *(const float4*)&in[(size_t)(r0 + r) * C + c0 + c];
    tile[r][c] = v.x; tile[r][c + 1] = v.y; tile[r][c + 2] = v.z; tile[r][c + 3] = v.w;
  }
  __syncthreads();
#pragma unroll
  for (int j = 0; j < 2; ++j) {
    const int wi = j * 256 + t;
    const int oc = wi >> 3;        // original col (0..63)
    const int orr = (wi & 7) * 8;  // original row chunk
    bf16x8 v;
#pragma unroll
    for (int u = 0; u < 8; ++u) v[u] = (bf16_t)tile[orr + u][oc];
    *(bf16x8*)&out[(size_t)(c0 + oc) * R + r0 + orr] = v;
  }
}

// ---------------------------------------------------------------------------
// LayerNorm over D=1024, f32 in -> bf16 out. One block (256 thr) per row.
__global__ __launch_bounds__(256) void ln_kernel(
    const float* __restrict__ x, const float* __restrict__ g,
    const float* __restrict__ b, bf16_t* __restrict__ out) {
  const int row = blockIdx.x;
  const int t = threadIdx.x;
  const float* xr = x + (size_t)row * DMODEL;
  float4 v = *(const float4*)&xr[t * 4];
  float s = v.x + v.y + v.z + v.w;
  float s2 = v.x * v.x + v.y * v.y + v.z * v.z + v.w * v.w;
#pragma unroll
  for (int off = 1; off < 64; off <<= 1) {
    s += __shfl_xor(s, off, 64);
    s2 += __shfl_xor(s2, off, 64);
  }
  __shared__ float ps[8];
  const int w = t >> 6;
  if ((t & 63) == 0) { ps[w] = s; ps[4 + w] = s2; }
  __syncthreads();
  s = ps[0] + ps[1] + ps[2] + ps[3];
  s2 = ps[4] + ps[5] + ps[6] + ps[7];
  const float mu = s / (float)DMODEL;
  const float var = s2 / (float)DMODEL - mu * mu;
  const float rstd = rsqrtf(var + 1e-5f);
  float4 gg = *(const float4*)&g[t * 4];
  float4 bb = *(const float4*)&b[t * 4];
  bf16x4 o;
  o[0] = (bf16_t)((v.x - mu) * rstd * gg.x + bb.x);
  o[1] = (bf16_t)((v.y - mu) * rstd * gg.y + bb.y);
  o[2] = (bf16_t)((v.z - mu) * rstd * gg.z + bb.z);
  o[3] = (bf16_t)((v.w - mu) * rstd * gg.w + bb.w);
  *(bf16x4*)&out[(size_t)row * DMODEL + t * 4] = o;
}

// ---------------------------------------------------------------------------
// Causal conv1d (k=4, left pad 3) along features + SiLU. f32 in, bf16 out.
__global__ __launch_bounds__(256) void conv_kernel(
    const float* __restrict__ xin, const float* __restrict__ cw,
    const float* __restrict__ cb, bf16_t* __restrict__ yb) {
  const size_t idx = (size_t)blockIdx.x * blockDim.x + threadIdx.x;  // one per 4 elems
  const int row = (int)(idx >> 9);  // 2048/4 = 512 chunks per row
  const int c0 = ((int)idx & 511) * 4;
  const float* xr = xin + (size_t)row * HDIM;
  const float w0 = cw[0], w1 = cw[1], w2 = cw[2], w3 = cw[3], bb = cb[0];
  float xm3 = 0.f, xm2 = 0.f, xm1 = 0.f;
  if (c0 > 0) { xm3 = xr[c0 - 3]; xm2 = xr[c0 - 2]; xm1 = xr[c0 - 1]; }
  float4 xv = *(const float4*)&xr[c0];
  float y0 = w0 * xm3 + w1 * xm2 + w2 * xm1 + w3 * xv.x + bb;
  float y1 = w0 * xm2 + w1 * xm1 + w2 * xv.x + w3 * xv.y + bb;
  float y2 = w0 * xm1 + w1 * xv.x + w2 * xv.y + w3 * xv.z + bb;
  float y3 = w0 * xv.x + w1 * xv.y + w2 * xv.z + w3 * xv.w + bb;
  y0 = siluf_(y0); y1 = siluf_(y1); y2 = siluf_(y2); y3 = siluf_(y3);
  bf16x4 yb4;
  yb4[0] = (bf16_t)y0; yb4[1] = (bf16_t)y1; yb4[2] = (bf16_t)y2; yb4[3] = (bf16_t)y3;
  *(bf16x4*)&yb[(size_t)row * HDIM + c0] = yb4;
}

// ---------------------------------------------------------------------------
// Gate kernel: elementwise over (B, H). Writes m_t, c_t, n_t (all f32 to d_out).
__global__ __launch_bounds__(256) void gate_kernel(
    const float* __restrict__ it, const float* __restrict__ ft,
    const float* __restrict__ mp, const float* __restrict__ cp,
    const float* __restrict__ np, const float* __restrict__ vv,
    const float* __restrict__ kk, float* __restrict__ m_out,
    float* __restrict__ c_out, float* __restrict__ n_out) {
  const size_t e = ((size_t)blockIdx.x * blockDim.x + threadIdx.x) * 4;
  float4 iv = *(const float4*)&it[e];
  float4 fv = *(const float4*)&ft[e];
  float4 mv = *(const float4*)&mp[e];
  float4 cv = *(const float4*)&cp[e];
  float4 nv = *(const float4*)&np[e];
  float4 vvv = *(const float4*)&vv[e];
  float4 kv = *(const float4*)&kk[e];
  float4 mo, co, no;
#pragma unroll
  for (int u = 0; u < 4; ++u) {
    float i1 = ((const float*)&iv)[u], f1 = ((const float*)&fv)[u];
    float m1 = ((const float*)&mv)[u], c1 = ((const float*)&cv)[u];
    float n1 = ((const float*)&nv)[u], v1 = ((const float*)&vvv)[u];
    float k1 = ((const float*)&kv)[u];
    float mt = fmaxf(f1 + m1, i1);
    float ig = __expf(i1 - mt);
    float fg = __expf(f1 + m1 - mt);
    ((float*)&mo)[u] = mt;
    ((float*)&co)[u] = fg * c1 + ig * (v1 * k1);
    ((float*)&no)[u] = fg * n1 + ig * k1;
  }
  *(float4*)&m_out[e] = mo;
  *(float4*)&c_out[e] = co;
  *(float4*)&n_out[e] = no;
}

// ---------------------------------------------------------------------------
// h_t + GroupNorm(8 groups of 256) + skip + silu-gate. One block per row.
__global__ __launch_bounds__(256) void hgn_kernel(
    const float* __restrict__ o_pre, const float* __restrict__ q,
    const float* __restrict__ c_t, const float* __restrict__ denomf,
    const float* __restrict__ skip, const float* __restrict__ upr,
    const float* __restrict__ gn_g, const float* __restrict__ gn_b,
    float* __restrict__ h_out, bf16_t* __restrict__ act_out) {
  const int row = blockIdx.x;
  const int t = threadIdx.x;
  const size_t base = (size_t)row * HDIM + t * 8;
  const int i0 = t * 8;
  float h[8];
  float s = 0.f, s2 = 0.f;
#pragma unroll
  for (int j = 0; j < 2; ++j) {
    float4 ov = *(const float4*)&o_pre[base + j * 4];
    float4 qv = *(const float4*)&q[base + j * 4];
    float4 cv = *(const float4*)&c_t[base + j * 4];
#pragma unroll
    for (int u = 0; u < 4; ++u) {
      const int k = j * 4 + u;
      float hv = sigmoidf_(((const float*)&ov)[u]) * ((const float*)&cv)[u] *
                 ((const float*)&qv)[u] / denomf[i0 + k];
      h[k] = hv;
      s += hv;
      s2 += hv * hv;
    }
  }
  // group = 256 channels = 32 threads; wave64 holds two groups, masks<32 stay in-group
#pragma unroll
  for (int off = 1; off < 32; off <<= 1) {
    s += __shfl_xor(s, off, 64);
    s2 += __shfl_xor(s2, off, 64);
  }
  const float mu = s / 256.f;
  const float var = s2 / 256.f - mu * mu;
  const float rstd = rsqrtf(var + 1e-5f);
  // write h_t
  float4 h0 = {h[0], h[1], h[2], h[3]};
  float4 h1 = {h[4], h[5], h[6], h[7]};
  *(float4*)&h_out[base] = h0;
  *(float4*)&h_out[base + 4] = h1;
  // groupnorm + skip + silu(upr)
  bf16x8 a8;
#pragma unroll
  for (int j = 0; j < 2; ++j) {
    float4 gv = *(const float4*)&gn_g[i0 + j * 4];
    float4 bv = *(const float4*)&gn_b[i0 + j * 4];
    float4 sv = *(const float4*)&skip[base + j * 4];
    float4 uv = *(const float4*)&upr[base + j * 4];
#pragma unroll
    for (int u = 0; u < 4; ++u) {
      const int k = j * 4 + u;
      float y = (h[k] - mu) * rstd * ((const float*)&gv)[u] + ((const float*)&bv)[u];
      y = (y + ((const float*)&sv)[u]) * siluf_(((const float*)&uv)[u]);
      a8[k] = (bf16_t)y;
    }
  }
  *(bf16x8*)&act_out[base] = a8;
}

// ---------------------------------------------------------------------------
// Generic bf16 MFMA GEMM: C[M,N] = A[M,K] @ Bt[N,K]^T  (Bt is N x K, k-major)
// 128x128 tile, BK=32, 4 waves (each 64x64 = 4x4 frags of 16x16x32).
// EPI: 0 = (acc + bias) * scale [+res] -> C (f32) [+Cb bf16]
//      1 = denom: atomicMax(dmax[row], |acc|) with max over all cols
template <int EPI, bool WB16, bool RES>
__global__ __launch_bounds__(256) void gemm_kernel(
    const bf16_t* __restrict__ A, int lda, const bf16_t* __restrict__ Bt, int ldb,
    const float* __restrict__ bias, float* __restrict__ C, int ldc,
    bf16_t* __restrict__ Cb, const float* __restrict__ res, int ldres,
    unsigned int* __restrict__ dmax, int K, float scale,
    int zA, long long zB, int zBias, int zC) {
  const int z = blockIdx.z;
  A += (size_t)z * zA;
  Bt += (size_t)z * zB;
  if (bias) bias += (size_t)z * zBias;
  if (EPI == 0) {
    C += (size_t)z * zC;
    if (WB16) Cb += (size_t)z * zC;
  }
  const int brow = blockIdx.y * 128;
  const int bcol = blockIdx.x * 128;
  __shared__ bf16_t As[128 * 32];
  __shared__ bf16_t Bs[128 * 32];
  const int tid = threadIdx.x;
  const int w = tid >> 6, l = tid & 63;
  const int wr = w >> 1, wc = w & 1;
  const int lr = l & 15, kg = l >> 4;
  const int l4 = l & 3, ld4 = l >> 2;

  f32x4 acc[4][4];
  const f32x4 fzero = {0.f, 0.f, 0.f, 0.f};
#pragma unroll
  for (int m = 0; m < 4; ++m)
#pragma unroll
    for (int n = 0; n < 4; ++n) acc[m][n] = fzero;

  for (int kt = 0; kt < K; kt += 32) {
#pragma unroll
    for (int j = 0; j < 2; ++j) {
      const int rowX = w * 32 + j * 16 + ld4;  // tile row staged by this lane
      gload_lds16(A + (size_t)(brow + rowX) * lda + kt + l4 * 8, &As[w * 1024 + j * 512]);
      gload_lds16(Bt + (size_t)(bcol + rowX) * ldb + kt + l4 * 8, &Bs[w * 1024 + j * 512]);
    }
    __syncthreads();
    bf16x8 a[4], b[4];
#pragma unroll
    for (int m = 0; m < 4; ++m)
      a[m] = *(const bf16x8*)&As[(wr * 64 + m * 16 + lr) * 32 + kg * 8];
#pragma unroll
    for (int n = 0; n < 4; ++n)
      b[n] = *(const bf16x8*)&Bs[(wc * 64 + n * 16 + lr) * 32 + kg * 8];
#pragma unroll
    for (int m = 0; m < 4; ++m)
#pragma unroll
      for (int n = 0; n < 4; ++n)
        acc[m][n] = __builtin_amdgcn_mfma_f32_16x16x32_bf16(a[m], b[n], acc[m][n], 0, 0, 0);
    __syncthreads();
  }

  if (EPI == 0) {
#pragma unroll
    for (int m = 0; m < 4; ++m) {
      const int row0 = brow + wr * 64 + m * 16 + kg * 4;
#pragma unroll
      for (int n = 0; n < 4; ++n) {
        const int col = bcol + wc * 64 + n * 16 + lr;
        const float bv = bias ? bias[col] : 0.f;
#pragma unroll
        for (int r = 0; r < 4; ++r) {
          const int row = row0 + r;
          float v = (acc[m][n][r] + bv) * scale;
          if (RES) v += res[(size_t)row * ldres + col];
          C[(size_t)row * ldc + col] = v;
          if (WB16) Cb[(size_t)row * ldc + col] = (bf16_t)v;
        }
      }
    }
  } else {
    // denom: per output row (i), max over cols j of |acc|
#pragma unroll
    for (int m = 0; m < 4; ++m) {
#pragma unroll
      for (int r = 0; r < 4; ++r) {
        float v = 0.f;
#pragma unroll
        for (int n = 0; n < 4; ++n) v = fmaxf(v, fabsf(acc[m][n][r]));
#pragma unroll
        for (int sft = 8; sft >= 1; sft >>= 1) v = fmaxf(v, __shfl_xor(v, sft, 64));
        if (lr == 0) {
          const int row = brow + wr * 64 + m * 16 + kg * 4 + r;
          atomicMax(&dmax[row], __float_as_uint(v));
        }
      }
    }
  }
}

// ---------------------------------------------------------------------------
extern "C" void kernel_launch(void* const* d_in, const int* in_sizes, int n_in,
                              void* d_out, int out_size, void* d_ws, size_t ws_size,
                              hipStream_t stream) {
  (void)in_sizes; (void)n_in; (void)out_size; (void)ws_size;
  const float* x      = (const float*)d_in[0];
  const float* ln_g   = (const float*)d_in[1];
  const float* ln_b   = (const float*)d_in[2];
  const float* Wupl   = (const float*)d_in[3];
  const float* bupl   = (const float*)d_in[4];
  const float* Wupr   = (const float*)d_in[5];
  const float* bupr   = (const float*)d_in[6];
  const float* conv_w = (const float*)d_in[7];
  const float* conv_b = (const float*)d_in[8];
  const float* Wskip  = (const float*)d_in[9];
  const float* bskip  = (const float*)d_in[10];
  const float* Wq     = (const float*)d_in[11];
  const float* bq     = (const float*)d_in[12];
  const float* Wk     = (const float*)d_in[13];
  const float* bk     = (const float*)d_in[14];
  const float* Wv     = (const float*)d_in[15];
  const float* bv     = (const float*)d_in[16];
  const float* Wi     = (const float*)d_in[17];
  const float* bi     = (const float*)d_in[18];
  const float* Wf     = (const float*)d_in[19];
  const float* bf_    = (const float*)d_in[20];
  const float* Wo     = (const float*)d_in[21];
  const float* bo     = (const float*)d_in[22];
  const float* gn_g   = (const float*)d_in[23];
  const float* gn_b   = (const float*)d_in[24];
  const float* Wdown  = (const float*)d_in[25];
  const float* bdown  = (const float*)d_in[26];
  const float* c_prev = (const float*)d_in[27];
  const float* n_prev = (const float*)d_in[28];
  const float* m_prev = (const float*)d_in[29];

  float* out_final = (float*)d_out;
  float* out_h = out_final + (size_t)B_ROWS * DMODEL;
  float* out_c = out_h + (size_t)B_ROWS * HDIM;
  float* out_n = out_c + (size_t)B_ROWS * HDIM;
  float* out_m = out_n + (size_t)B_ROWS * HDIM;

  char* ws = (char*)d_ws;
  size_t off = 0;
  auto alloc = [&](size_t bytes) -> void* {
    off = (off + 255) & ~(size_t)255;
    void* p = ws + off;
    off += bytes;
    return p;
  };
  const size_t BH = (size_t)B_ROWS * HDIM;   // 16M elems
  const size_t BD = (size_t)B_ROWS * DMODEL; // 8M elems

  bf16_t* WuplT = (bf16_t*)alloc((size_t)DMODEL * HDIM * 2);
  bf16_t* WuprT = (bf16_t*)alloc((size_t)DMODEL * HDIM * 2);
  bf16_t* WskipT = (bf16_t*)alloc((size_t)HDIM * HDIM * 2);
  bf16_t* WiT = (bf16_t*)alloc((size_t)HDIM * HDIM * 2);
  bf16_t* WfT = (bf16_t*)alloc((size_t)HDIM * HDIM * 2);
  bf16_t* WoT = (bf16_t*)alloc((size_t)HDIM * HDIM * 2);
  bf16_t* WdownT = (bf16_t*)alloc((size_t)HDIM * DMODEL * 2);
  bf16_t* WqT = (bf16_t*)alloc((size_t)8 * 256 * 256 * 2);
  bf16_t* WkT = (bf16_t*)alloc((size_t)8 * 256 * 256 * 2);
  bf16_t* WvT = (bf16_t*)alloc((size_t)8 * 256 * 256 * 2);
  bf16_t* xnorm_b = (bf16_t*)alloc(BD * 2);
  float*  xupl_f = (float*)alloc(BH * 4);
  bf16_t* xupl_b = (bf16_t*)alloc(BH * 2);
  float*  xupr_f = (float*)alloc(BH * 4);
  bf16_t* xconv_b = (bf16_t*)alloc(BH * 2);
  float*  xskip_f = (float*)alloc(BH * 4);
  float*  q_f = (float*)alloc(BH * 4);
  float*  k_f = (float*)alloc(BH * 4);
  float*  v_f = (float*)alloc(BH * 4);
  float*  i_f = (float*)alloc(BH * 4);
  float*  f_f = (float*)alloc(BH * 4);
  float*  o_f = (float*)alloc(BH * 4);
  bf16_t* qT_b = (bf16_t*)alloc(BH * 2);
  bf16_t* nT_b = (bf16_t*)alloc(BH * 2);
  bf16_t* act_b = (bf16_t*)alloc(BH * 2);
  unsigned int* dmax = (unsigned int*)alloc(HDIM * 4);

  // ---- weights: transpose + convert to bf16 (N x K layout)
  wtrans_kernel<<<dim3(HDIM / 64, DMODEL / 64, 1), 256, 0, stream>>>(Wupl, WuplT, DMODEL, HDIM);
  wtrans_kernel<<<dim3(HDIM / 64, DMODEL / 64, 1), 256, 0, stream>>>(Wupr, WuprT, DMODEL, HDIM);
  wtrans_kernel<<<dim3(HDIM / 64, HDIM / 64, 1), 256, 0, stream>>>(Wskip, WskipT, HDIM, HDIM);
  wtrans_kernel<<<dim3(HDIM / 64, HDIM / 64, 1), 256, 0, stream>>>(Wi, WiT, HDIM, HDIM);
  wtrans_kernel<<<dim3(HDIM / 64, HDIM / 64, 1), 256, 0, stream>>>(Wf, WfT, HDIM, HDIM);
  wtrans_kernel<<<dim3(HDIM / 64, HDIM / 64, 1), 256, 0, stream>>>(Wo, WoT, HDIM, HDIM);
  wtrans_kernel<<<dim3(DMODEL / 64, HDIM / 64, 1), 256, 0, stream>>>(Wdown, WdownT, HDIM, DMODEL);
  wtrans_kernel<<<dim3(4, 4, 8), 256, 0, stream>>>(Wq, WqT, 256, 256);
  wtrans_kernel<<<dim3(4, 4, 8), 256, 0, stream>>>(Wk, WkT, 256, 256);
  wtrans_kernel<<<dim3(4, 4, 8), 256, 0, stream>>>(Wv, WvT, 256, 256);

  // ---- layernorm
  ln_kernel<<<B_ROWS, 256, 0, stream>>>(x, ln_g, ln_b, xnorm_b);

  // ---- up projections
  gemm_kernel<0, true, false><<<dim3(HDIM / 128, B_ROWS / 128, 1), 256, 0, stream>>>(
      xnorm_b, DMODEL, WuplT, DMODEL, bupl, xupl_f, HDIM, xupl_b, nullptr, 0, nullptr,
      DMODEL, 1.f, 0, 0, 0, 0);
  gemm_kernel<0, false, false><<<dim3(HDIM / 128, B_ROWS / 128, 1), 256, 0, stream>>>(
      xnorm_b, DMODEL, WuprT, DMODEL, bupr, xupr_f, HDIM, nullptr, nullptr, 0, nullptr,
      DMODEL, 1.f, 0, 0, 0, 0);

  // ---- causal conv + silu
  conv_kernel<<<(unsigned)(BH / 4 / 256), 256, 0, stream>>>(xupl_f, conv_w, conv_b, xconv_b);

  // ---- H x H projections
  gemm_kernel<0, false, false><<<dim3(HDIM / 128, B_ROWS / 128, 1), 256, 0, stream>>>(
      xconv_b, HDIM, WskipT, HDIM, bskip, xskip_f, HDIM, nullptr, nullptr, 0, nullptr,
      HDIM, 1.f, 0, 0, 0, 0);
  gemm_kernel<0, false, false><<<dim3(HDIM / 128, B_ROWS / 128, 1), 256, 0, stream>>>(
      xconv_b, HDIM, WiT, HDIM, bi, i_f, HDIM, nullptr, nullptr, 0, nullptr,
      HDIM, 1.f, 0, 0, 0, 0);
  gemm_kernel<0, false, false><<<dim3(HDIM / 128, B_ROWS / 128, 1), 256, 0, stream>>>(
      xconv_b, HDIM, WfT, HDIM, bf_, f_f, HDIM, nullptr, nullptr, 0, nullptr,
      HDIM, 1.f, 0, 0, 0, 0);
  gemm_kernel<0, false, false><<<dim3(HDIM / 128, B_ROWS / 128, 1), 256, 0, stream>>>(
      xupl_b, HDIM, WoT, HDIM, bo, o_f, HDIM, nullptr, nullptr, 0, nullptr,
      HDIM, 1.f, 0, 0, 0, 0);

  // ---- block-diagonal q, k, v (grid.z = 8 blocks of 256x256)
  gemm_kernel<0, false, false><<<dim3(2, B_ROWS / 128, 8), 256, 0, stream>>>(
      xconv_b, HDIM, WqT, 256, bq, q_f, HDIM, nullptr, nullptr, 0, nullptr,
      256, 1.f, 256, 256 * 256, 256, 256);
  gemm_kernel<0, false, false><<<dim3(2, B_ROWS / 128, 8), 256, 0, stream>>>(
      xconv_b, HDIM, WkT, 256, bk, k_f, HDIM, nullptr, nullptr, 0, nullptr,
      256, 0.0625f, 256, 256 * 256, 256, 256);
  gemm_kernel<0, false, false><<<dim3(2, B_ROWS / 128, 8), 256, 0, stream>>>(
      xupl_b, HDIM, WvT, 256, bv, v_f, HDIM, nullptr, nullptr, 0, nullptr,
      256, 1.f, 256, 256 * 256, 256, 256);

  // ---- gates -> m_t, c_t, n_t
  gate_kernel<<<(unsigned)(BH / 4 / 256), 256, 0, stream>>>(
      i_f, f_f, m_prev, c_prev, n_prev, v_f, k_f, out_m, out_c, out_n);

  // ---- transpose q and n_t to k-major bf16 for the denom GEMM
  wtrans_kernel<<<dim3(HDIM / 64, B_ROWS / 64, 1), 256, 0, stream>>>(q_f, qT_b, B_ROWS, HDIM);
  wtrans_kernel<<<dim3(HDIM / 64, B_ROWS / 64, 1), 256, 0, stream>>>(out_n, nT_b, B_ROWS, HDIM);

  // ---- denom[i] = max_j |sum_b n_t[b,i] q[b,j]|
  hipMemsetAsync(dmax, 0, HDIM * 4, stream);
  gemm_kernel<1, false, false><<<dim3(HDIM / 128, HDIM / 128, 1), 256, 0, stream>>>(
      nT_b, B_ROWS, qT_b, B_ROWS, nullptr, nullptr, 0, nullptr, nullptr, 0, dmax,
      B_ROWS, 1.f, 0, 0, 0, 0);

  // ---- h_t + groupnorm + skip + silu gate
  hgn_kernel<<<B_ROWS, 256, 0, stream>>>(o_f, q_f, out_c, (const float*)dmax, xskip_f,
                                         xupr_f, gn_g, gn_b, out_h, act_b);

  // ---- down projection + residual
  gemm_kernel<0, false, true><<<dim3(DMODEL / 128, B_ROWS / 128, 1), 256, 0, stream>>>(
      act_b, HDIM, WdownT, HDIM, bdown, out_final, DMODEL, nullptr, x, DMODEL, nullptr,
      HDIM, 1.f, 0, 0, 0, 0);
}

// Round 3
// 1546.395 us; speedup vs baseline: 1.1288x; 1.1288x over previous
//
#include <hip/hip_runtime.h>

// mLSTM block forward, MI355X gfx950.
// Round 3: split-K denom (occupancy fix, was 186us @ 11% occ), gate fused into
// dual-B i/f GEMM, bf16 intermediates (xupl/xupr/skip/o/k/v).

typedef __bf16 bf16_t;
typedef bf16_t bf16x8 __attribute__((ext_vector_type(8)));
typedef bf16_t bf16x4 __attribute__((ext_vector_type(4)));
typedef float f32x4 __attribute__((ext_vector_type(4)));

#define B_ROWS 8192
#define DMODEL 1024
#define HDIM   2048

__device__ __forceinline__ void gload_lds16(const void* g, void* s) {
  __builtin_amdgcn_global_load_lds(
      (const __attribute__((address_space(1))) void*)g,
      (__attribute__((address_space(3))) void*)s, 16, 0, 0);
}

__device__ __forceinline__ float sigmoidf_(float x) { return 1.f / (1.f + __expf(-x)); }
__device__ __forceinline__ float siluf_(float x)    { return x / (1.f + __expf(-x)); }

// ---------------------------------------------------------------------------
// Transpose + convert: in f32 (R x C) -> out bf16 (C x R). Batched over z.
__global__ __launch_bounds__(256) void wtrans_kernel(
    const float* __restrict__ in, bf16_t* __restrict__ out, int R, int C) {
  const int z = blockIdx.z;
  in  += (size_t)z * R * C;
  out += (size_t)z * R * C;
  __shared__ float tile[64][65];
  const int t = threadIdx.x;
  const int r0 = blockIdx.y * 64, c0 = blockIdx.x * 64;
#pragma unroll
  for (int j = 0; j < 4; ++j) {
    const int r = j * 16 + (t >> 4);
    const int c = (t & 15) * 4;
    float4 v = *(const float4*)&in[(size_t)(r0 + r) * C + c0 + c];
    tile[r][c] = v.x; tile[r][c + 1] = v.y; tile[r][c + 2] = v.z; tile[r][c + 3] = v.w;
  }
  __syncthreads();
#pragma unroll
  for (int j = 0; j < 2; ++j) {
    const int wi = j * 256 + t;
    const int oc = wi >> 3;
    const int orr = (wi & 7) * 8;
    bf16x8 v;
#pragma unroll
    for (int u = 0; u < 8; ++u) v[u] = (bf16_t)tile[orr + u][oc];
    *(bf16x8*)&out[(size_t)(c0 + oc) * R + r0 + orr] = v;
  }
}

// ---------------------------------------------------------------------------
// LayerNorm over D=1024, f32 in -> bf16 out. One block (256 thr) per row.
__global__ __launch_bounds__(256) void ln_kernel(
    const float* __restrict__ x, const float* __restrict__ g,
    const float* __restrict__ b, bf16_t* __restrict__ out) {
  const int row = blockIdx.x;
  const int t = threadIdx.x;
  const float* xr = x + (size_t)row * DMODEL;
  float4 v = *(const float4*)&xr[t * 4];
  float s = v.x + v.y + v.z + v.w;
  float s2 = v.x * v.x + v.y * v.y + v.z * v.z + v.w * v.w;
#pragma unroll
  for (int off = 1; off < 64; off <<= 1) {
    s += __shfl_xor(s, off, 64);
    s2 += __shfl_xor(s2, off, 64);
  }
  __shared__ float ps[8];
  const int w = t >> 6;
  if ((t & 63) == 0) { ps[w] = s; ps[4 + w] = s2; }
  __syncthreads();
  s = ps[0] + ps[1] + ps[2] + ps[3];
  s2 = ps[4] + ps[5] + ps[6] + ps[7];
  const float mu = s / (float)DMODEL;
  const float var = s2 / (float)DMODEL - mu * mu;
  const float rstd = rsqrtf(var + 1e-5f);
  float4 gg = *(const float4*)&g[t * 4];
  float4 bb = *(const float4*)&b[t * 4];
  bf16x4 o;
  o[0] = (bf16_t)((v.x - mu) * rstd * gg.x + bb.x);
  o[1] = (bf16_t)((v.y - mu) * rstd * gg.y + bb.y);
  o[2] = (bf16_t)((v.z - mu) * rstd * gg.z + bb.z);
  o[3] = (bf16_t)((v.w - mu) * rstd * gg.w + bb.w);
  *(bf16x4*)&out[(size_t)row * DMODEL + t * 4] = o;
}

// ---------------------------------------------------------------------------
// Causal conv1d (k=4, left pad 3) + SiLU. bf16 in -> bf16 out.
__global__ __launch_bounds__(256) void conv_kernel(
    const bf16_t* __restrict__ xin, const float* __restrict__ cw,
    const float* __restrict__ cb, bf16_t* __restrict__ yb) {
  const size_t idx = (size_t)blockIdx.x * blockDim.x + threadIdx.x;
  const int row = (int)(idx >> 9);
  const int c0 = ((int)idx & 511) * 4;
  const bf16_t* xr = xin + (size_t)row * HDIM;
  const float w0 = cw[0], w1 = cw[1], w2 = cw[2], w3 = cw[3], bb = cb[0];
  float xm3 = 0.f, xm2 = 0.f, xm1 = 0.f;
  if (c0 > 0) {
    bf16x4 p = *(const bf16x4*)&xr[c0 - 4];
    xm3 = (float)p[1]; xm2 = (float)p[2]; xm1 = (float)p[3];
  }
  bf16x4 xv4 = *(const bf16x4*)&xr[c0];
  float x0 = (float)xv4[0], x1 = (float)xv4[1], x2 = (float)xv4[2], x3 = (float)xv4[3];
  float y0 = w0 * xm3 + w1 * xm2 + w2 * xm1 + w3 * x0 + bb;
  float y1 = w0 * xm2 + w1 * xm1 + w2 * x0 + w3 * x1 + bb;
  float y2 = w0 * xm1 + w1 * x0 + w2 * x1 + w3 * x2 + bb;
  float y3 = w0 * x0 + w1 * x1 + w2 * x2 + w3 * x3 + bb;
  bf16x4 yb4;
  yb4[0] = (bf16_t)siluf_(y0); yb4[1] = (bf16_t)siluf_(y1);
  yb4[2] = (bf16_t)siluf_(y2); yb4[3] = (bf16_t)siluf_(y3);
  *(bf16x4*)&yb[(size_t)row * HDIM + c0] = yb4;
}

// ---------------------------------------------------------------------------
// h_t + GroupNorm(8 groups of 256) + skip + silu-gate. One block per row.
__global__ __launch_bounds__(256) void hgn_kernel(
    const bf16_t* __restrict__ o_pre, const float* __restrict__ q,
    const float* __restrict__ c_t, const float* __restrict__ denomf,
    const bf16_t* __restrict__ skip, const bf16_t* __restrict__ upr,
    const float* __restrict__ gn_g, const float* __restrict__ gn_b,
    float* __restrict__ h_out, bf16_t* __restrict__ act_out) {
  const int row = blockIdx.x;
  const int t = threadIdx.x;
  const size_t base = (size_t)row * HDIM + t * 8;
  const int i0 = t * 8;
  bf16x8 o8 = *(const bf16x8*)&o_pre[base];
  float h[8];
  float s = 0.f, s2 = 0.f;
#pragma unroll
  for (int j = 0; j < 2; ++j) {
    float4 qv = *(const float4*)&q[base + j * 4];
    float4 cv = *(const float4*)&c_t[base + j * 4];
#pragma unroll
    for (int u = 0; u < 4; ++u) {
      const int k = j * 4 + u;
      float hv = sigmoidf_((float)o8[k]) * ((const float*)&cv)[u] *
                 ((const float*)&qv)[u] / denomf[i0 + k];
      h[k] = hv;
      s += hv;
      s2 += hv * hv;
    }
  }
#pragma unroll
  for (int off = 1; off < 32; off <<= 1) {
    s += __shfl_xor(s, off, 64);
    s2 += __shfl_xor(s2, off, 64);
  }
  const float mu = s / 256.f;
  const float var = s2 / 256.f - mu * mu;
  const float rstd = rsqrtf(var + 1e-5f);
  float4 h0 = {h[0], h[1], h[2], h[3]};
  float4 h1 = {h[4], h[5], h[6], h[7]};
  *(float4*)&h_out[base] = h0;
  *(float4*)&h_out[base + 4] = h1;
  bf16x8 sk8 = *(const bf16x8*)&skip[base];
  bf16x8 up8 = *(const bf16x8*)&upr[base];
  bf16x8 a8;
#pragma unroll
  for (int j = 0; j < 2; ++j) {
    float4 gv = *(const float4*)&gn_g[i0 + j * 4];
    float4 bv = *(const float4*)&gn_b[i0 + j * 4];
#pragma unroll
    for (int u = 0; u < 4; ++u) {
      const int k = j * 4 + u;
      float y = (h[k] - mu) * rstd * ((const float*)&gv)[u] + ((const float*)&bv)[u];
      y = (y + (float)sk8[k]) * siluf_((float)up8[k]);
      a8[k] = (bf16_t)y;
    }
  }
  *(bf16x8*)&act_out[base] = a8;
}

// ---------------------------------------------------------------------------
// Generic bf16 MFMA GEMM: C[M,N] = A[M,K] @ Bt[N,K]^T  (Bt is N x K, k-major)
// 128x128 tile, BK=32, 4 waves. OUTMODE: 0 = f32 C, 2 = bf16 Cb. RES adds res.
template <int OUTMODE, bool RES>
__global__ __launch_bounds__(256) void gemm_kernel(
    const bf16_t* __restrict__ A, int lda, const bf16_t* __restrict__ Bt, int ldb,
    const float* __restrict__ bias, float* __restrict__ C, bf16_t* __restrict__ Cb,
    int ldc, const float* __restrict__ res, int ldres, int K, float scale,
    int zA, long long zB, int zBias, int zC) {
  const int z = blockIdx.z;
  A += (size_t)z * zA;
  Bt += (size_t)z * zB;
  if (bias) bias += (size_t)z * zBias;
  if (OUTMODE == 0) C += (size_t)z * zC; else Cb += (size_t)z * zC;
  const int brow = blockIdx.y * 128;
  const int bcol = blockIdx.x * 128;
  __shared__ bf16_t As[128 * 32];
  __shared__ bf16_t Bs[128 * 32];
  const int tid = threadIdx.x;
  const int w = tid >> 6, l = tid & 63;
  const int wr = w >> 1, wc = w & 1;
  const int lr = l & 15, kg = l >> 4;
  const int l4 = l & 3, ld4 = l >> 2;

  f32x4 acc[4][4];
  const f32x4 fzero = {0.f, 0.f, 0.f, 0.f};
#pragma unroll
  for (int m = 0; m < 4; ++m)
#pragma unroll
    for (int n = 0; n < 4; ++n) acc[m][n] = fzero;

  for (int kt = 0; kt < K; kt += 32) {
#pragma unroll
    for (int j = 0; j < 2; ++j) {
      const int rowX = w * 32 + j * 16 + ld4;
      gload_lds16(A + (size_t)(brow + rowX) * lda + kt + l4 * 8, &As[w * 1024 + j * 512]);
      gload_lds16(Bt + (size_t)(bcol + rowX) * ldb + kt + l4 * 8, &Bs[w * 1024 + j * 512]);
    }
    __syncthreads();
    bf16x8 a[4], b[4];
#pragma unroll
    for (int m = 0; m < 4; ++m)
      a[m] = *(const bf16x8*)&As[(wr * 64 + m * 16 + lr) * 32 + kg * 8];
#pragma unroll
    for (int n = 0; n < 4; ++n)
      b[n] = *(const bf16x8*)&Bs[(wc * 64 + n * 16 + lr) * 32 + kg * 8];
#pragma unroll
    for (int m = 0; m < 4; ++m)
#pragma unroll
      for (int n = 0; n < 4; ++n)
        acc[m][n] = __builtin_amdgcn_mfma_f32_16x16x32_bf16(a[m], b[n], acc[m][n], 0, 0, 0);
    __syncthreads();
  }

#pragma unroll
  for (int m = 0; m < 4; ++m) {
    const int row0 = brow + wr * 64 + m * 16 + kg * 4;
#pragma unroll
    for (int n = 0; n < 4; ++n) {
      const int col = bcol + wc * 64 + n * 16 + lr;
      const float bv = bias ? bias[col] : 0.f;
#pragma unroll
      for (int r = 0; r < 4; ++r) {
        const int row = row0 + r;
        float v = (acc[m][n][r] + bv) * scale;
        if (RES) v += res[(size_t)row * ldres + col];
        if (OUTMODE == 0) C[(size_t)row * ldc + col] = v;
        else Cb[(size_t)row * ldc + col] = (bf16_t)v;
      }
    }
  }
}

// ---------------------------------------------------------------------------
// Dual-B GEMM + fused mLSTM gate. 128x64 tile (BN=64), both i and f tiles for
// the same output patch; epilogue computes m_t/c_t/n_t directly.
__global__ __launch_bounds__(256) void gemm_ifgate_kernel(
    const bf16_t* __restrict__ A,           // xconv [B][H]
    const bf16_t* __restrict__ Bi, const bf16_t* __restrict__ Bf,  // [H][H] k-major
    const float* __restrict__ bi, const float* __restrict__ bfv,
    const float* __restrict__ m_prev, const float* __restrict__ c_prev,
    const float* __restrict__ n_prev,
    const bf16_t* __restrict__ vb, const bf16_t* __restrict__ kb,
    float* __restrict__ m_out, float* __restrict__ c_out, float* __restrict__ n_out) {
  const int brow = blockIdx.y * 128;
  const int bcol = blockIdx.x * 64;
  __shared__ bf16_t As[128 * 32];
  __shared__ bf16_t Bis[64 * 32];
  __shared__ bf16_t Bfs[64 * 32];
  const int tid = threadIdx.x;
  const int w = tid >> 6, l = tid & 63;
  const int wr = w >> 1, wc = w & 1;
  const int lr = l & 15, kg = l >> 4;
  const int l4 = l & 3, ld4 = l >> 2;

  f32x4 acci[4][2], accf[4][2];
  const f32x4 fzero = {0.f, 0.f, 0.f, 0.f};
#pragma unroll
  for (int m = 0; m < 4; ++m)
#pragma unroll
    for (int n = 0; n < 2; ++n) { acci[m][n] = fzero; accf[m][n] = fzero; }

  for (int kt = 0; kt < HDIM; kt += 32) {
#pragma unroll
    for (int j = 0; j < 2; ++j) {
      const int rowX = w * 32 + j * 16 + ld4;
      gload_lds16(A + (size_t)(brow + rowX) * HDIM + kt + l4 * 8, &As[w * 1024 + j * 512]);
    }
    const int rowB = bcol + w * 16 + ld4;
    gload_lds16(Bi + (size_t)rowB * HDIM + kt + l4 * 8, &Bis[w * 512]);
    gload_lds16(Bf + (size_t)rowB * HDIM + kt + l4 * 8, &Bfs[w * 512]);
    __syncthreads();
    bf16x8 a[4], b1[2], b2[2];
#pragma unroll
    for (int m = 0; m < 4; ++m)
      a[m] = *(const bf16x8*)&As[(wr * 64 + m * 16 + lr) * 32 + kg * 8];
#pragma unroll
    for (int n = 0; n < 2; ++n) {
      b1[n] = *(const bf16x8*)&Bis[(wc * 32 + n * 16 + lr) * 32 + kg * 8];
      b2[n] = *(const bf16x8*)&Bfs[(wc * 32 + n * 16 + lr) * 32 + kg * 8];
    }
#pragma unroll
    for (int m = 0; m < 4; ++m)
#pragma unroll
      for (int n = 0; n < 2; ++n) {
        acci[m][n] = __builtin_amdgcn_mfma_f32_16x16x32_bf16(a[m], b1[n], acci[m][n], 0, 0, 0);
        accf[m][n] = __builtin_amdgcn_mfma_f32_16x16x32_bf16(a[m], b2[n], accf[m][n], 0, 0, 0);
      }
    __syncthreads();
  }

#pragma unroll
  for (int m = 0; m < 4; ++m) {
    const int row0 = brow + wr * 64 + m * 16 + kg * 4;
#pragma unroll
    for (int n = 0; n < 2; ++n) {
      const int col = bcol + wc * 32 + n * 16 + lr;
      const float biv = bi[col], bfvv = bfv[col];
#pragma unroll
      for (int r = 0; r < 4; ++r) {
        const int row = row0 + r;
        const size_t idx = (size_t)row * HDIM + col;
        const float it = acci[m][n][r] + biv;
        const float ft = accf[m][n][r] + bfvv;
        const float m1 = m_prev[idx];
        const float mt = fmaxf(ft + m1, it);
        const float ig = __expf(it - mt);
        const float fg = __expf(ft + m1 - mt);
        const float v1 = (float)vb[idx], k1 = (float)kb[idx];
        m_out[idx] = mt;
        c_out[idx] = fg * c_prev[idx] + ig * (v1 * k1);
        n_out[idx] = fg * n_prev[idx] + ig * k1;
      }
    }
  }
}

// ---------------------------------------------------------------------------
// denom reduce: dmax[i] = max_j |sum_z part[z][i][j]|
__global__ __launch_bounds__(256) void denom_reduce_kernel(
    const float* __restrict__ part, float* __restrict__ dmaxf) {
  const int i = blockIdx.x;
  const int t = threadIdx.x;
  float vmax = 0.f;
#pragma unroll
  for (int u = 0; u < 8; ++u) {
    const int j = u * 256 + t;
    float s = 0.f;
#pragma unroll
    for (int zz = 0; zz < 8; ++zz)
      s += part[(size_t)zz * HDIM * HDIM + (size_t)i * HDIM + j];
    vmax = fmaxf(vmax, fabsf(s));
  }
#pragma unroll
  for (int off = 1; off < 64; off <<= 1) vmax = fmaxf(vmax, __shfl_xor(vmax, off, 64));
  __shared__ float ps[4];
  if ((t & 63) == 0) ps[t >> 6] = vmax;
  __syncthreads();
  if (t == 0) dmaxf[i] = fmaxf(fmaxf(ps[0], ps[1]), fmaxf(ps[2], ps[3]));
}

// ---------------------------------------------------------------------------
extern "C" void kernel_launch(void* const* d_in, const int* in_sizes, int n_in,
                              void* d_out, int out_size, void* d_ws, size_t ws_size,
                              hipStream_t stream) {
  (void)in_sizes; (void)n_in; (void)out_size; (void)ws_size;
  const float* x      = (const float*)d_in[0];
  const float* ln_g   = (const float*)d_in[1];
  const float* ln_b   = (const float*)d_in[2];
  const float* Wupl   = (const float*)d_in[3];
  const float* bupl   = (const float*)d_in[4];
  const float* Wupr   = (const float*)d_in[5];
  const float* bupr   = (const float*)d_in[6];
  const float* conv_w = (const float*)d_in[7];
  const float* conv_b = (const float*)d_in[8];
  const float* Wskip  = (const float*)d_in[9];
  const float* bskip  = (const float*)d_in[10];
  const float* Wq     = (const float*)d_in[11];
  const float* bq     = (const float*)d_in[12];
  const float* Wk     = (const float*)d_in[13];
  const float* bk     = (const float*)d_in[14];
  const float* Wv     = (const float*)d_in[15];
  const float* bv     = (const float*)d_in[16];
  const float* Wi     = (const float*)d_in[17];
  const float* bi     = (const float*)d_in[18];
  const float* Wf     = (const float*)d_in[19];
  const float* bf_    = (const float*)d_in[20];
  const float* Wo     = (const float*)d_in[21];
  const float* bo     = (const float*)d_in[22];
  const float* gn_g   = (const float*)d_in[23];
  const float* gn_b   = (const float*)d_in[24];
  const float* Wdown  = (const float*)d_in[25];
  const float* bdown  = (const float*)d_in[26];
  const float* c_prev = (const float*)d_in[27];
  const float* n_prev = (const float*)d_in[28];
  const float* m_prev = (const float*)d_in[29];

  float* out_final = (float*)d_out;
  float* out_h = out_final + (size_t)B_ROWS * DMODEL;
  float* out_c = out_h + (size_t)B_ROWS * HDIM;
  float* out_n = out_c + (size_t)B_ROWS * HDIM;
  float* out_m = out_n + (size_t)B_ROWS * HDIM;

  char* ws = (char*)d_ws;
  size_t off = 0;
  auto alloc = [&](size_t bytes) -> void* {
    off = (off + 255) & ~(size_t)255;
    void* p = ws + off;
    off += bytes;
    return p;
  };
  const size_t BH = (size_t)B_ROWS * HDIM;
  const size_t BD = (size_t)B_ROWS * DMODEL;

  bf16_t* WuplT = (bf16_t*)alloc((size_t)DMODEL * HDIM * 2);
  bf16_t* WuprT = (bf16_t*)alloc((size_t)DMODEL * HDIM * 2);
  bf16_t* WskipT = (bf16_t*)alloc((size_t)HDIM * HDIM * 2);
  bf16_t* WiT = (bf16_t*)alloc((size_t)HDIM * HDIM * 2);
  bf16_t* WfT = (bf16_t*)alloc((size_t)HDIM * HDIM * 2);
  bf16_t* WoT = (bf16_t*)alloc((size_t)HDIM * HDIM * 2);
  bf16_t* WdownT = (bf16_t*)alloc((size_t)HDIM * DMODEL * 2);
  bf16_t* WqT = (bf16_t*)alloc((size_t)8 * 256 * 256 * 2);
  bf16_t* WkT = (bf16_t*)alloc((size_t)8 * 256 * 256 * 2);
  bf16_t* WvT = (bf16_t*)alloc((size_t)8 * 256 * 256 * 2);
  bf16_t* xnorm_b = (bf16_t*)alloc(BD * 2);
  bf16_t* xupl_b = (bf16_t*)alloc(BH * 2);
  bf16_t* xupr_b = (bf16_t*)alloc(BH * 2);
  bf16_t* xconv_b = (bf16_t*)alloc(BH * 2);
  bf16_t* xskip_b = (bf16_t*)alloc(BH * 2);
  bf16_t* o_b = (bf16_t*)alloc(BH * 2);
  float*  q_f = (float*)alloc(BH * 4);
  bf16_t* k_b = (bf16_t*)alloc(BH * 2);
  bf16_t* v_b = (bf16_t*)alloc(BH * 2);
  bf16_t* qT_b = (bf16_t*)alloc(BH * 2);
  bf16_t* nT_b = (bf16_t*)alloc(BH * 2);
  bf16_t* act_b = (bf16_t*)alloc(BH * 2);
  float*  part = (float*)alloc((size_t)8 * HDIM * HDIM * 4);
  float*  dmaxf = (float*)alloc(HDIM * 4);

  // ---- weights: transpose + convert to bf16 (N x K layout)
  wtrans_kernel<<<dim3(HDIM / 64, DMODEL / 64, 1), 256, 0, stream>>>(Wupl, WuplT, DMODEL, HDIM);
  wtrans_kernel<<<dim3(HDIM / 64, DMODEL / 64, 1), 256, 0, stream>>>(Wupr, WuprT, DMODEL, HDIM);
  wtrans_kernel<<<dim3(HDIM / 64, HDIM / 64, 1), 256, 0, stream>>>(Wskip, WskipT, HDIM, HDIM);
  wtrans_kernel<<<dim3(HDIM / 64, HDIM / 64, 1), 256, 0, stream>>>(Wi, WiT, HDIM, HDIM);
  wtrans_kernel<<<dim3(HDIM / 64, HDIM / 64, 1), 256, 0, stream>>>(Wf, WfT, HDIM, HDIM);
  wtrans_kernel<<<dim3(HDIM / 64, HDIM / 64, 1), 256, 0, stream>>>(Wo, WoT, HDIM, HDIM);
  wtrans_kernel<<<dim3(DMODEL / 64, HDIM / 64, 1), 256, 0, stream>>>(Wdown, WdownT, HDIM, DMODEL);
  wtrans_kernel<<<dim3(4, 4, 8), 256, 0, stream>>>(Wq, WqT, 256, 256);
  wtrans_kernel<<<dim3(4, 4, 8), 256, 0, stream>>>(Wk, WkT, 256, 256);
  wtrans_kernel<<<dim3(4, 4, 8), 256, 0, stream>>>(Wv, WvT, 256, 256);

  // ---- layernorm
  ln_kernel<<<B_ROWS, 256, 0, stream>>>(x, ln_g, ln_b, xnorm_b);

  // ---- up projections (bf16 outputs)
  gemm_kernel<2, false><<<dim3(HDIM / 128, B_ROWS / 128, 1), 256, 0, stream>>>(
      xnorm_b, DMODEL, WuplT, DMODEL, bupl, nullptr, xupl_b, HDIM, nullptr, 0,
      DMODEL, 1.f, 0, 0, 0, 0);
  gemm_kernel<2, false><<<dim3(HDIM / 128, B_ROWS / 128, 1), 256, 0, stream>>>(
      xnorm_b, DMODEL, WuprT, DMODEL, bupr, nullptr, xupr_b, HDIM, nullptr, 0,
      DMODEL, 1.f, 0, 0, 0, 0);

  // ---- causal conv + silu
  conv_kernel<<<(unsigned)(BH / 4 / 256), 256, 0, stream>>>(xupl_b, conv_w, conv_b, xconv_b);

  // ---- skip and o projections (bf16 out)
  gemm_kernel<2, false><<<dim3(HDIM / 128, B_ROWS / 128, 1), 256, 0, stream>>>(
      xconv_b, HDIM, WskipT, HDIM, bskip, nullptr, xskip_b, HDIM, nullptr, 0,
      HDIM, 1.f, 0, 0, 0, 0);
  gemm_kernel<2, false><<<dim3(HDIM / 128, B_ROWS / 128, 1), 256, 0, stream>>>(
      xupl_b, HDIM, WoT, HDIM, bo, nullptr, o_b, HDIM, nullptr, 0,
      HDIM, 1.f, 0, 0, 0, 0);

  // ---- block-diagonal q (f32), k (bf16, /16), v (bf16)
  gemm_kernel<0, false><<<dim3(2, B_ROWS / 128, 8), 256, 0, stream>>>(
      xconv_b, HDIM, WqT, 256, bq, q_f, nullptr, HDIM, nullptr, 0,
      256, 1.f, 256, 256 * 256, 256, 256);
  gemm_kernel<2, false><<<dim3(2, B_ROWS / 128, 8), 256, 0, stream>>>(
      xconv_b, HDIM, WkT, 256, bk, nullptr, k_b, HDIM, nullptr, 0,
      256, 0.0625f, 256, 256 * 256, 256, 256);
  gemm_kernel<2, false><<<dim3(2, B_ROWS / 128, 8), 256, 0, stream>>>(
      xupl_b, HDIM, WvT, 256, bv, nullptr, v_b, HDIM, nullptr, 0,
      256, 1.f, 256, 256 * 256, 256, 256);

  // ---- i/f dual GEMM + fused gate -> m_t, c_t, n_t
  gemm_ifgate_kernel<<<dim3(HDIM / 64, B_ROWS / 128, 1), 256, 0, stream>>>(
      xconv_b, WiT, WfT, bi, bf_, m_prev, c_prev, n_prev, v_b, k_b,
      out_m, out_c, out_n);

  // ---- transpose q and n_t to k-major bf16 for the denom GEMM
  wtrans_kernel<<<dim3(HDIM / 64, B_ROWS / 64, 1), 256, 0, stream>>>(q_f, qT_b, B_ROWS, HDIM);
  wtrans_kernel<<<dim3(HDIM / 64, B_ROWS / 64, 1), 256, 0, stream>>>(out_n, nT_b, B_ROWS, HDIM);

  // ---- denom: split-K GEMM (partials) + reduce
  gemm_kernel<0, false><<<dim3(HDIM / 128, HDIM / 128, 8), 256, 0, stream>>>(
      nT_b, B_ROWS, qT_b, B_ROWS, nullptr, part, nullptr, HDIM, nullptr, 0,
      1024, 1.f, 1024, 1024, 0, HDIM * HDIM);
  denom_reduce_kernel<<<HDIM, 256, 0, stream>>>(part, dmaxf);

  // ---- h_t + groupnorm + skip + silu gate
  hgn_kernel<<<B_ROWS, 256, 0, stream>>>(o_b, q_f, out_c, dmaxf, xskip_b,
                                         xupr_b, gn_g, gn_b, out_h, act_b);

  // ---- down projection + residual
  gemm_kernel<0, true><<<dim3(DMODEL / 128, B_ROWS / 128, 1), 256, 0, stream>>>(
      act_b, HDIM, WdownT, HDIM, bdown, out_final, nullptr, DMODEL, x, DMODEL,
      HDIM, 1.f, 0, 0, 0, 0);
}

// Round 4
// 1351.399 us; speedup vs baseline: 1.2917x; 1.1443x over previous
//
#include <hip/hip_runtime.h>

// mLSTM block forward, MI355X gfx950.
// Round 4: 256^2 / BK=64 / 8-wave deep-pipelined GEMM (T1+T2+T4+T5):
//   counted vmcnt(8) across raw barriers, XOR-swizzled LDS (both-sides),
//   setprio around MFMA clusters, XCD-swizzled block ids.
// Heavy GEMMs (upl/upr/skip/o/if-dual/denom/down) use it; qkv stay 128^2.

typedef __bf16 bf16_t;
typedef bf16_t bf16x8 __attribute__((ext_vector_type(8)));
typedef bf16_t bf16x4 __attribute__((ext_vector_type(4)));
typedef float f32x4 __attribute__((ext_vector_type(4)));

#define B_ROWS 8192
#define DMODEL 1024
#define HDIM   2048

__device__ __forceinline__ void gload_lds16(const void* g, void* s) {
  __builtin_amdgcn_global_load_lds(
      (const __attribute__((address_space(1))) void*)g,
      (__attribute__((address_space(3))) void*)s, 16, 0, 0);
}

__device__ __forceinline__ float sigmoidf_(float x) { return 1.f / (1.f + __expf(-x)); }
__device__ __forceinline__ float siluf_(float x)    { return x / (1.f + __expf(-x)); }

// Bijective XCD swizzle of a linear block id (T1, m204 variant).
__device__ __forceinline__ int xcd_swz(int lin, int nwg) {
  const int q = nwg >> 3, r = nwg & 7;
  const int xcd = lin & 7, sub = lin >> 3;
  return (xcd < r ? xcd * (q + 1) : r * (q + 1) + (xcd - r) * q) + sub;
}

// ---------------------------------------------------------------------------
// Transpose + convert: in f32 (R x C) -> out bf16 (C x R). Batched over z.
__global__ __launch_bounds__(256) void wtrans_kernel(
    const float* __restrict__ in, bf16_t* __restrict__ out, int R, int C) {
  const int z = blockIdx.z;
  in  += (size_t)z * R * C;
  out += (size_t)z * R * C;
  __shared__ float tile[64][65];
  const int t = threadIdx.x;
  const int r0 = blockIdx.y * 64, c0 = blockIdx.x * 64;
#pragma unroll
  for (int j = 0; j < 4; ++j) {
    const int r = j * 16 + (t >> 4);
    const int c = (t & 15) * 4;
    float4 v = *(const float4*)&in[(size_t)(r0 + r) * C + c0 + c];
    tile[r][c] = v.x; tile[r][c + 1] = v.y; tile[r][c + 2] = v.z; tile[r][c + 3] = v.w;
  }
  __syncthreads();
#pragma unroll
  for (int j = 0; j < 2; ++j) {
    const int wi = j * 256 + t;
    const int oc = wi >> 3;
    const int orr = (wi & 7) * 8;
    bf16x8 v;
#pragma unroll
    for (int u = 0; u < 8; ++u) v[u] = (bf16_t)tile[orr + u][oc];
    *(bf16x8*)&out[(size_t)(c0 + oc) * R + r0 + orr] = v;
  }
}

// ---------------------------------------------------------------------------
// LayerNorm over D=1024, f32 in -> bf16 out. One block (256 thr) per row.
__global__ __launch_bounds__(256) void ln_kernel(
    const float* __restrict__ x, const float* __restrict__ g,
    const float* __restrict__ b, bf16_t* __restrict__ out) {
  const int row = blockIdx.x;
  const int t = threadIdx.x;
  const float* xr = x + (size_t)row * DMODEL;
  float4 v = *(const float4*)&xr[t * 4];
  float s = v.x + v.y + v.z + v.w;
  float s2 = v.x * v.x + v.y * v.y + v.z * v.z + v.w * v.w;
#pragma unroll
  for (int off = 1; off < 64; off <<= 1) {
    s += __shfl_xor(s, off, 64);
    s2 += __shfl_xor(s2, off, 64);
  }
  __shared__ float ps[8];
  const int w = t >> 6;
  if ((t & 63) == 0) { ps[w] = s; ps[4 + w] = s2; }
  __syncthreads();
  s = ps[0] + ps[1] + ps[2] + ps[3];
  s2 = ps[4] + ps[5] + ps[6] + ps[7];
  const float mu = s / (float)DMODEL;
  const float var = s2 / (float)DMODEL - mu * mu;
  const float rstd = rsqrtf(var + 1e-5f);
  float4 gg = *(const float4*)&g[t * 4];
  float4 bb = *(const float4*)&b[t * 4];
  bf16x4 o;
  o[0] = (bf16_t)((v.x - mu) * rstd * gg.x + bb.x);
  o[1] = (bf16_t)((v.y - mu) * rstd * gg.y + bb.y);
  o[2] = (bf16_t)((v.z - mu) * rstd * gg.z + bb.z);
  o[3] = (bf16_t)((v.w - mu) * rstd * gg.w + bb.w);
  *(bf16x4*)&out[(size_t)row * DMODEL + t * 4] = o;
}

// ---------------------------------------------------------------------------
// Causal conv1d (k=4, left pad 3) + SiLU. bf16 in -> bf16 out.
__global__ __launch_bounds__(256) void conv_kernel(
    const bf16_t* __restrict__ xin, const float* __restrict__ cw,
    const float* __restrict__ cb, bf16_t* __restrict__ yb) {
  const size_t idx = (size_t)blockIdx.x * blockDim.x + threadIdx.x;
  const int row = (int)(idx >> 9);
  const int c0 = ((int)idx & 511) * 4;
  const bf16_t* xr = xin + (size_t)row * HDIM;
  const float w0 = cw[0], w1 = cw[1], w2 = cw[2], w3 = cw[3], bb = cb[0];
  float xm3 = 0.f, xm2 = 0.f, xm1 = 0.f;
  if (c0 > 0) {
    bf16x4 p = *(const bf16x4*)&xr[c0 - 4];
    xm3 = (float)p[1]; xm2 = (float)p[2]; xm1 = (float)p[3];
  }
  bf16x4 xv4 = *(const bf16x4*)&xr[c0];
  float x0 = (float)xv4[0], x1 = (float)xv4[1], x2 = (float)xv4[2], x3 = (float)xv4[3];
  float y0 = w0 * xm3 + w1 * xm2 + w2 * xm1 + w3 * x0 + bb;
  float y1 = w0 * xm2 + w1 * xm1 + w2 * x0 + w3 * x1 + bb;
  float y2 = w0 * xm1 + w1 * x0 + w2 * x1 + w3 * x2 + bb;
  float y3 = w0 * x0 + w1 * x1 + w2 * x2 + w3 * x3 + bb;
  bf16x4 yb4;
  yb4[0] = (bf16_t)siluf_(y0); yb4[1] = (bf16_t)siluf_(y1);
  yb4[2] = (bf16_t)siluf_(y2); yb4[3] = (bf16_t)siluf_(y3);
  *(bf16x4*)&yb[(size_t)row * HDIM + c0] = yb4;
}

// ---------------------------------------------------------------------------
// h_t + GroupNorm(8 groups of 256) + skip + silu-gate. One block per row.
__global__ __launch_bounds__(256) void hgn_kernel(
    const bf16_t* __restrict__ o_pre, const float* __restrict__ q,
    const float* __restrict__ c_t, const float* __restrict__ denomf,
    const bf16_t* __restrict__ skip, const bf16_t* __restrict__ upr,
    const float* __restrict__ gn_g, const float* __restrict__ gn_b,
    float* __restrict__ h_out, bf16_t* __restrict__ act_out) {
  const int row = blockIdx.x;
  const int t = threadIdx.x;
  const size_t base = (size_t)row * HDIM + t * 8;
  const int i0 = t * 8;
  bf16x8 o8 = *(const bf16x8*)&o_pre[base];
  float h[8];
  float s = 0.f, s2 = 0.f;
#pragma unroll
  for (int j = 0; j < 2; ++j) {
    float4 qv = *(const float4*)&q[base + j * 4];
    float4 cv = *(const float4*)&c_t[base + j * 4];
#pragma unroll
    for (int u = 0; u < 4; ++u) {
      const int k = j * 4 + u;
      float hv = sigmoidf_((float)o8[k]) * ((const float*)&cv)[u] *
                 ((const float*)&qv)[u] / denomf[i0 + k];
      h[k] = hv;
      s += hv;
      s2 += hv * hv;
    }
  }
#pragma unroll
  for (int off = 1; off < 32; off <<= 1) {
    s += __shfl_xor(s, off, 64);
    s2 += __shfl_xor(s2, off, 64);
  }
  const float mu = s / 256.f;
  const float var = s2 / 256.f - mu * mu;
  const float rstd = rsqrtf(var + 1e-5f);
  float4 h0 = {h[0], h[1], h[2], h[3]};
  float4 h1 = {h[4], h[5], h[6], h[7]};
  *(float4*)&h_out[base] = h0;
  *(float4*)&h_out[base + 4] = h1;
  bf16x8 sk8 = *(const bf16x8*)&skip[base];
  bf16x8 up8 = *(const bf16x8*)&upr[base];
  bf16x8 a8;
#pragma unroll
  for (int j = 0; j < 2; ++j) {
    float4 gv = *(const float4*)&gn_g[i0 + j * 4];
    float4 bv = *(const float4*)&gn_b[i0 + j * 4];
#pragma unroll
    for (int u = 0; u < 4; ++u) {
      const int k = j * 4 + u;
      float y = (h[k] - mu) * rstd * ((const float*)&gv)[u] + ((const float*)&bv)[u];
      y = (y + (float)sk8[k]) * siluf_((float)up8[k]);
      a8[k] = (bf16_t)y;
    }
  }
  *(bf16x8*)&act_out[base] = a8;
}

// ---------------------------------------------------------------------------
// 128^2 / BK=32 GEMM (kept for small block-diagonal qkv).
template <int OUTMODE, bool RES>
__global__ __launch_bounds__(256) void gemm_kernel(
    const bf16_t* __restrict__ A, int lda, const bf16_t* __restrict__ Bt, int ldb,
    const float* __restrict__ bias, float* __restrict__ C, bf16_t* __restrict__ Cb,
    int ldc, const float* __restrict__ res, int ldres, int K, float scale,
    int zA, long long zB, int zBias, int zC) {
  const int z = blockIdx.z;
  A += (size_t)z * zA;
  Bt += (size_t)z * zB;
  if (bias) bias += (size_t)z * zBias;
  if (OUTMODE == 0) C += (size_t)z * zC; else Cb += (size_t)z * zC;
  const int brow = blockIdx.y * 128;
  const int bcol = blockIdx.x * 128;
  __shared__ bf16_t As[128 * 32];
  __shared__ bf16_t Bs[128 * 32];
  const int tid = threadIdx.x;
  const int w = tid >> 6, l = tid & 63;
  const int wr = w >> 1, wc = w & 1;
  const int lr = l & 15, kg = l >> 4;
  const int l4 = l & 3, ld4 = l >> 2;

  f32x4 acc[4][4];
  const f32x4 fzero = {0.f, 0.f, 0.f, 0.f};
#pragma unroll
  for (int m = 0; m < 4; ++m)
#pragma unroll
    for (int n = 0; n < 4; ++n) acc[m][n] = fzero;

  for (int kt = 0; kt < K; kt += 32) {
#pragma unroll
    for (int j = 0; j < 2; ++j) {
      const int rowX = w * 32 + j * 16 + ld4;
      gload_lds16(A + (size_t)(brow + rowX) * lda + kt + l4 * 8, &As[w * 1024 + j * 512]);
      gload_lds16(Bt + (size_t)(bcol + rowX) * ldb + kt + l4 * 8, &Bs[w * 1024 + j * 512]);
    }
    __syncthreads();
    bf16x8 a[4], b[4];
#pragma unroll
    for (int m = 0; m < 4; ++m)
      a[m] = *(const bf16x8*)&As[(wr * 64 + m * 16 + lr) * 32 + kg * 8];
#pragma unroll
    for (int n = 0; n < 4; ++n)
      b[n] = *(const bf16x8*)&Bs[(wc * 64 + n * 16 + lr) * 32 + kg * 8];
#pragma unroll
    for (int m = 0; m < 4; ++m)
#pragma unroll
      for (int n = 0; n < 4; ++n)
        acc[m][n] = __builtin_amdgcn_mfma_f32_16x16x32_bf16(a[m], b[n], acc[m][n], 0, 0, 0);
    __syncthreads();
  }

#pragma unroll
  for (int m = 0; m < 4; ++m) {
    const int row0 = brow + wr * 64 + m * 16 + kg * 4;
#pragma unroll
    for (int n = 0; n < 4; ++n) {
      const int col = bcol + wc * 64 + n * 16 + lr;
      const float bv = bias ? bias[col] : 0.f;
#pragma unroll
      for (int r = 0; r < 4; ++r) {
        const int row = row0 + r;
        float v = (acc[m][n][r] + bv) * scale;
        if (RES) v += res[(size_t)row * ldres + col];
        if (OUTMODE == 0) C[(size_t)row * ldc + col] = v;
        else Cb[(size_t)row * ldc + col] = (bf16_t)v;
      }
    }
  }
}

// ---------------------------------------------------------------------------
// 256^2 / BK=64 / 8-wave deep-pipelined GEMM.
// LDS 128 KiB double-buffer; counted vmcnt(8) (8 gloads/thread/K-tile stay in
// flight across raw barriers); XOR-swizzled LDS (slot ^= row&7, both-sides);
// setprio around MFMA clusters. C = A[M,K] @ Bt[N,K]^T.
template <int OUTMODE /*0=f32,2=bf16*/, bool RES>
__global__ __launch_bounds__(512, 2) void gemm256_kernel(
    const bf16_t* __restrict__ A, int lda, const bf16_t* __restrict__ Bt, int ldb,
    const float* __restrict__ bias, float* __restrict__ C, bf16_t* __restrict__ Cb,
    int ldc, const float* __restrict__ res, int ldres, int K, float scale,
    long long zA, long long zB, long long zC) {
  const int z = blockIdx.z;
  A += (size_t)z * zA;
  Bt += (size_t)z * zB;
  if (OUTMODE == 0) C += (size_t)z * zC; else Cb += (size_t)z * zC;

  const int nwg = gridDim.x * gridDim.y;
  const int lin2 = xcd_swz(blockIdx.y * gridDim.x + blockIdx.x, nwg);
  const int bx = lin2 % gridDim.x, by = lin2 / gridDim.x;
  const int brow = by * 256, bcol = bx * 256;

  __shared__ bf16_t As[2][256 * 64];
  __shared__ bf16_t Bs[2][256 * 64];

  const int tid = threadIdx.x;
  const int l = tid & 63;
  const int w = tid >> 6;
  const int wr = w >> 2, wn = w & 3;        // 2 (M) x 4 (N) waves
  const int lr = l & 15, kg = l >> 4;
  const int srow = tid >> 3;                // staging row within 64-row group
  const int sslot = (tid & 7) ^ (srow & 7); // inverse-swizzled global 16B slot

  f32x4 acc[8][4];
  const f32x4 fzero = {0.f, 0.f, 0.f, 0.f};
#pragma unroll
  for (int m = 0; m < 8; ++m)
#pragma unroll
    for (int n = 0; n < 4; ++n) acc[m][n] = fzero;

  const int NT = K >> 6;
  const bf16_t* Ag = A + (size_t)brow * lda;
  const bf16_t* Bg = Bt + (size_t)bcol * ldb;

  auto stage = [&](int t, int buf) {
    const size_t kof = (size_t)t * 64 + sslot * 8;
#pragma unroll
    for (int j = 0; j < 4; ++j) {
      const int r = j * 64 + srow;
      gload_lds16(Ag + (size_t)r * lda + kof, (char*)&As[buf][0] + (j * 512 + tid) * 16);
      gload_lds16(Bg + (size_t)r * ldb + kof, (char*)&Bs[buf][0] + (j * 512 + tid) * 16);
    }
  };

  stage(0, 0);
  stage(1, 1);

  for (int t = 0; t < NT; ++t) {
    if (t < NT - 1) asm volatile("s_waitcnt vmcnt(8)" ::: "memory");
    else            asm volatile("s_waitcnt vmcnt(0)" ::: "memory");
    __builtin_amdgcn_s_barrier();
    const int buf = t & 1;
#pragma unroll
    for (int kk = 0; kk < 2; ++kk) {
      bf16x8 a[8], b[4];
#pragma unroll
      for (int n = 0; n < 4; ++n) {
        const int r = wn * 64 + n * 16 + lr;
        b[n] = *(const bf16x8*)&Bs[buf][r * 64 + (((kk * 4 + kg) ^ (r & 7)) * 8)];
      }
#pragma unroll
      for (int m = 0; m < 8; ++m) {
        const int r = wr * 128 + m * 16 + lr;
        a[m] = *(const bf16x8*)&As[buf][r * 64 + (((kk * 4 + kg) ^ (r & 7)) * 8)];
      }
      __builtin_amdgcn_s_setprio(1);
#pragma unroll
      for (int m = 0; m < 8; ++m)
#pragma unroll
        for (int n = 0; n < 4; ++n)
          acc[m][n] = __builtin_amdgcn_mfma_f32_16x16x32_bf16(a[m], b[n], acc[m][n], 0, 0, 0);
      __builtin_amdgcn_s_setprio(0);
    }
    asm volatile("s_waitcnt lgkmcnt(0)" ::: "memory");
    __builtin_amdgcn_sched_barrier(0);
    __builtin_amdgcn_s_barrier();
    if (t + 2 < NT) stage(t + 2, buf);
  }

#pragma unroll
  for (int m = 0; m < 8; ++m) {
    const int row0 = brow + wr * 128 + m * 16 + kg * 4;
#pragma unroll
    for (int n = 0; n < 4; ++n) {
      const int col = bcol + wn * 64 + n * 16 + lr;
      const float bvv = bias ? bias[col] : 0.f;
#pragma unroll
      for (int r = 0; r < 4; ++r) {
        const int row = row0 + r;
        float v = (acc[m][n][r] + bvv) * scale;
        if (RES) v += res[(size_t)row * ldres + col];
        if (OUTMODE == 0) C[(size_t)row * ldc + col] = v;
        else Cb[(size_t)row * ldc + col] = (bf16_t)v;
      }
    }
  }
}

// ---------------------------------------------------------------------------
// 256x128 dual-B deep-pipelined GEMM + fused mLSTM gate epilogue.
// Same staging budget (8 loads/thread/K-tile: 4 A + 2 Bi + 2 Bf) => same
// vmcnt(8) pipeline as gemm256.
__global__ __launch_bounds__(512, 2) void ifgate256_kernel(
    const bf16_t* __restrict__ A,                                  // xconv [B][H]
    const bf16_t* __restrict__ Bi, const bf16_t* __restrict__ Bf,  // [H][H] k-major
    const float* __restrict__ bi, const float* __restrict__ bfv,
    const float* __restrict__ m_prev, const float* __restrict__ c_prev,
    const float* __restrict__ n_prev,
    const bf16_t* __restrict__ vb, const bf16_t* __restrict__ kb,
    float* __restrict__ m_out, float* __restrict__ c_out, float* __restrict__ n_out) {
  const int nwg = gridDim.x * gridDim.y;
  const int lin2 = xcd_swz(blockIdx.y * gridDim.x + blockIdx.x, nwg);
  const int bx = lin2 % gridDim.x, by = lin2 / gridDim.x;
  const int brow = by * 256, bcol = bx * 128;

  __shared__ bf16_t As[2][256 * 64];
  __shared__ bf16_t Bis[2][128 * 64];
  __shared__ bf16_t Bfs[2][128 * 64];

  const int tid = threadIdx.x;
  const int l = tid & 63;
  const int w = tid >> 6;
  const int wr = w >> 2, wn = w & 3;        // 2 (M) x 4 (N/32) waves
  const int lr = l & 15, kg = l >> 4;
  const int srow = tid >> 3;
  const int sslot = (tid & 7) ^ (srow & 7);

  f32x4 acci[8][2], accf[8][2];
  const f32x4 fzero = {0.f, 0.f, 0.f, 0.f};
#pragma unroll
  for (int m = 0; m < 8; ++m)
#pragma unroll
    for (int n = 0; n < 2; ++n) { acci[m][n] = fzero; accf[m][n] = fzero; }

  const int NT = HDIM >> 6;
  const bf16_t* Ag = A + (size_t)brow * HDIM;
  const bf16_t* Big = Bi + (size_t)bcol * HDIM;
  const bf16_t* Bfg = Bf + (size_t)bcol * HDIM;

  auto stage = [&](int t, int buf) {
    const size_t kof = (size_t)t * 64 + sslot * 8;
#pragma unroll
    for (int j = 0; j < 4; ++j) {
      const int r = j * 64 + srow;
      gload_lds16(Ag + (size_t)r * HDIM + kof, (char*)&As[buf][0] + (j * 512 + tid) * 16);
    }
#pragma unroll
    for (int j = 0; j < 2; ++j) {
      const int r = j * 64 + srow;
      gload_lds16(Big + (size_t)r * HDIM + kof, (char*)&Bis[buf][0] + (j * 512 + tid) * 16);
      gload_lds16(Bfg + (size_t)r * HDIM + kof, (char*)&Bfs[buf][0] + (j * 512 + tid) * 16);
    }
  };

  stage(0, 0);
  stage(1, 1);

  for (int t = 0; t < NT; ++t) {
    if (t < NT - 1) asm volatile("s_waitcnt vmcnt(8)" ::: "memory");
    else            asm volatile("s_waitcnt vmcnt(0)" ::: "memory");
    __builtin_amdgcn_s_barrier();
    const int buf = t & 1;
#pragma unroll
    for (int kk = 0; kk < 2; ++kk) {
      bf16x8 a[8], b1[2], b2[2];
#pragma unroll
      for (int n = 0; n < 2; ++n) {
        const int r = wn * 32 + n * 16 + lr;
        const int eo = r * 64 + (((kk * 4 + kg) ^ (r & 7)) * 8);
        b1[n] = *(const bf16x8*)&Bis[buf][eo];
        b2[n] = *(const bf16x8*)&Bfs[buf][eo];
      }
#pragma unroll
      for (int m = 0; m < 8; ++m) {
        const int r = wr * 128 + m * 16 + lr;
        a[m] = *(const bf16x8*)&As[buf][r * 64 + (((kk * 4 + kg) ^ (r & 7)) * 8)];
      }
      __builtin_amdgcn_s_setprio(1);
#pragma unroll
      for (int m = 0; m < 8; ++m)
#pragma unroll
        for (int n = 0; n < 2; ++n) {
          acci[m][n] = __builtin_amdgcn_mfma_f32_16x16x32_bf16(a[m], b1[n], acci[m][n], 0, 0, 0);
          accf[m][n] = __builtin_amdgcn_mfma_f32_16x16x32_bf16(a[m], b2[n], accf[m][n], 0, 0, 0);
        }
      __builtin_amdgcn_s_setprio(0);
    }
    asm volatile("s_waitcnt lgkmcnt(0)" ::: "memory");
    __builtin_amdgcn_sched_barrier(0);
    __builtin_amdgcn_s_barrier();
    if (t + 2 < NT) stage(t + 2, buf);
  }

#pragma unroll
  for (int m = 0; m < 8; ++m) {
    const int row0 = brow + wr * 128 + m * 16 + kg * 4;
#pragma unroll
    for (int n = 0; n < 2; ++n) {
      const int col = bcol + wn * 32 + n * 16 + lr;
      const float biv = bi[col], bfvv = bfv[col];
#pragma unroll
      for (int r = 0; r < 4; ++r) {
        const int row = row0 + r;
        const size_t idx = (size_t)row * HDIM + col;
        const float it = acci[m][n][r] + biv;
        const float ft = accf[m][n][r] + bfvv;
        const float m1 = m_prev[idx];
        const float mt = fmaxf(ft + m1, it);
        const float ig = __expf(it - mt);
        const float fg = __expf(ft + m1 - mt);
        const float v1 = (float)vb[idx], k1 = (float)kb[idx];
        m_out[idx] = mt;
        c_out[idx] = fg * c_prev[idx] + ig * (v1 * k1);
        n_out[idx] = fg * n_prev[idx] + ig * k1;
      }
    }
  }
}

// ---------------------------------------------------------------------------
// denom reduce: dmax[i] = max_j |sum_z part[z][i][j]| (4 split-K parts)
__global__ __launch_bounds__(256) void denom_reduce_kernel(
    const float* __restrict__ part, float* __restrict__ dmaxf) {
  const int i = blockIdx.x;
  const int t = threadIdx.x;
  float vmax = 0.f;
#pragma unroll
  for (int u = 0; u < 8; ++u) {
    const int j = u * 256 + t;
    float s = 0.f;
#pragma unroll
    for (int zz = 0; zz < 4; ++zz)
      s += part[(size_t)zz * HDIM * HDIM + (size_t)i * HDIM + j];
    vmax = fmaxf(vmax, fabsf(s));
  }
#pragma unroll
  for (int off = 1; off < 64; off <<= 1) vmax = fmaxf(vmax, __shfl_xor(vmax, off, 64));
  __shared__ float ps[4];
  if ((t & 63) == 0) ps[t >> 6] = vmax;
  __syncthreads();
  if (t == 0) dmaxf[i] = fmaxf(fmaxf(ps[0], ps[1]), fmaxf(ps[2], ps[3]));
}

// ---------------------------------------------------------------------------
extern "C" void kernel_launch(void* const* d_in, const int* in_sizes, int n_in,
                              void* d_out, int out_size, void* d_ws, size_t ws_size,
                              hipStream_t stream) {
  (void)in_sizes; (void)n_in; (void)out_size; (void)ws_size;
  const float* x      = (const float*)d_in[0];
  const float* ln_g   = (const float*)d_in[1];
  const float* ln_b   = (const float*)d_in[2];
  const float* Wupl   = (const float*)d_in[3];
  const float* bupl   = (const float*)d_in[4];
  const float* Wupr   = (const float*)d_in[5];
  const float* bupr   = (const float*)d_in[6];
  const float* conv_w = (const float*)d_in[7];
  const float* conv_b = (const float*)d_in[8];
  const float* Wskip  = (const float*)d_in[9];
  const float* bskip  = (const float*)d_in[10];
  const float* Wq     = (const float*)d_in[11];
  const float* bq     = (const float*)d_in[12];
  const float* Wk     = (const float*)d_in[13];
  const float* bk     = (const float*)d_in[14];
  const float* Wv     = (const float*)d_in[15];
  const float* bv     = (const float*)d_in[16];
  const float* Wi     = (const float*)d_in[17];
  const float* bi     = (const float*)d_in[18];
  const float* Wf     = (const float*)d_in[19];
  const float* bf_    = (const float*)d_in[20];
  const float* Wo     = (const float*)d_in[21];
  const float* bo     = (const float*)d_in[22];
  const float* gn_g   = (const float*)d_in[23];
  const float* gn_b   = (const float*)d_in[24];
  const float* Wdown  = (const float*)d_in[25];
  const float* bdown  = (const float*)d_in[26];
  const float* c_prev = (const float*)d_in[27];
  const float* n_prev = (const float*)d_in[28];
  const float* m_prev = (const float*)d_in[29];

  float* out_final = (float*)d_out;
  float* out_h = out_final + (size_t)B_ROWS * DMODEL;
  float* out_c = out_h + (size_t)B_ROWS * HDIM;
  float* out_n = out_c + (size_t)B_ROWS * HDIM;
  float* out_m = out_n + (size_t)B_ROWS * HDIM;

  char* ws = (char*)d_ws;
  size_t off = 0;
  auto alloc = [&](size_t bytes) -> void* {
    off = (off + 255) & ~(size_t)255;
    void* p = ws + off;
    off += bytes;
    return p;
  };
  const size_t BH = (size_t)B_ROWS * HDIM;
  const size_t BD = (size_t)B_ROWS * DMODEL;

  bf16_t* WuplT = (bf16_t*)alloc((size_t)DMODEL * HDIM * 2);
  bf16_t* WuprT = (bf16_t*)alloc((size_t)DMODEL * HDIM * 2);
  bf16_t* WskipT = (bf16_t*)alloc((size_t)HDIM * HDIM * 2);
  bf16_t* WiT = (bf16_t*)alloc((size_t)HDIM * HDIM * 2);
  bf16_t* WfT = (bf16_t*)alloc((size_t)HDIM * HDIM * 2);
  bf16_t* WoT = (bf16_t*)alloc((size_t)HDIM * HDIM * 2);
  bf16_t* WdownT = (bf16_t*)alloc((size_t)HDIM * DMODEL * 2);
  bf16_t* WqT = (bf16_t*)alloc((size_t)8 * 256 * 256 * 2);
  bf16_t* WkT = (bf16_t*)alloc((size_t)8 * 256 * 256 * 2);
  bf16_t* WvT = (bf16_t*)alloc((size_t)8 * 256 * 256 * 2);
  bf16_t* xnorm_b = (bf16_t*)alloc(BD * 2);
  bf16_t* xupl_b = (bf16_t*)alloc(BH * 2);
  bf16_t* xupr_b = (bf16_t*)alloc(BH * 2);
  bf16_t* xconv_b = (bf16_t*)alloc(BH * 2);
  bf16_t* xskip_b = (bf16_t*)alloc(BH * 2);
  bf16_t* o_b = (bf16_t*)alloc(BH * 2);
  float*  q_f = (float*)alloc(BH * 4);
  bf16_t* k_b = (bf16_t*)alloc(BH * 2);
  bf16_t* v_b = (bf16_t*)alloc(BH * 2);
  bf16_t* qT_b = (bf16_t*)alloc(BH * 2);
  bf16_t* nT_b = (bf16_t*)alloc(BH * 2);
  bf16_t* act_b = (bf16_t*)alloc(BH * 2);
  float*  part = (float*)alloc((size_t)4 * HDIM * HDIM * 4);
  float*  dmaxf = (float*)alloc(HDIM * 4);

  // ---- weights: transpose + convert to bf16 (N x K layout)
  wtrans_kernel<<<dim3(HDIM / 64, DMODEL / 64, 1), 256, 0, stream>>>(Wupl, WuplT, DMODEL, HDIM);
  wtrans_kernel<<<dim3(HDIM / 64, DMODEL / 64, 1), 256, 0, stream>>>(Wupr, WuprT, DMODEL, HDIM);
  wtrans_kernel<<<dim3(HDIM / 64, HDIM / 64, 1), 256, 0, stream>>>(Wskip, WskipT, HDIM, HDIM);
  wtrans_kernel<<<dim3(HDIM / 64, HDIM / 64, 1), 256, 0, stream>>>(Wi, WiT, HDIM, HDIM);
  wtrans_kernel<<<dim3(HDIM / 64, HDIM / 64, 1), 256, 0, stream>>>(Wf, WfT, HDIM, HDIM);
  wtrans_kernel<<<dim3(HDIM / 64, HDIM / 64, 1), 256, 0, stream>>>(Wo, WoT, HDIM, HDIM);
  wtrans_kernel<<<dim3(DMODEL / 64, HDIM / 64, 1), 256, 0, stream>>>(Wdown, WdownT, HDIM, DMODEL);
  wtrans_kernel<<<dim3(4, 4, 8), 256, 0, stream>>>(Wq, WqT, 256, 256);
  wtrans_kernel<<<dim3(4, 4, 8), 256, 0, stream>>>(Wk, WkT, 256, 256);
  wtrans_kernel<<<dim3(4, 4, 8), 256, 0, stream>>>(Wv, WvT, 256, 256);

  // ---- layernorm
  ln_kernel<<<B_ROWS, 256, 0, stream>>>(x, ln_g, ln_b, xnorm_b);

  // ---- up projections (bf16 outputs)
  gemm256_kernel<2, false><<<dim3(HDIM / 256, B_ROWS / 256, 1), 512, 0, stream>>>(
      xnorm_b, DMODEL, WuplT, DMODEL, bupl, nullptr, xupl_b, HDIM, nullptr, 0,
      DMODEL, 1.f, 0, 0, 0);
  gemm256_kernel<2, false><<<dim3(HDIM / 256, B_ROWS / 256, 1), 512, 0, stream>>>(
      xnorm_b, DMODEL, WuprT, DMODEL, bupr, nullptr, xupr_b, HDIM, nullptr, 0,
      DMODEL, 1.f, 0, 0, 0);

  // ---- causal conv + silu
  conv_kernel<<<(unsigned)(BH / 4 / 256), 256, 0, stream>>>(xupl_b, conv_w, conv_b, xconv_b);

  // ---- skip and o projections (bf16 out)
  gemm256_kernel<2, false><<<dim3(HDIM / 256, B_ROWS / 256, 1), 512, 0, stream>>>(
      xconv_b, HDIM, WskipT, HDIM, bskip, nullptr, xskip_b, HDIM, nullptr, 0,
      HDIM, 1.f, 0, 0, 0);
  gemm256_kernel<2, false><<<dim3(HDIM / 256, B_ROWS / 256, 1), 512, 0, stream>>>(
      xupl_b, HDIM, WoT, HDIM, bo, nullptr, o_b, HDIM, nullptr, 0,
      HDIM, 1.f, 0, 0, 0);

  // ---- block-diagonal q (f32), k (bf16, /16), v (bf16) — small K, old kernel
  gemm_kernel<0, false><<<dim3(2, B_ROWS / 128, 8), 256, 0, stream>>>(
      xconv_b, HDIM, WqT, 256, bq, q_f, nullptr, HDIM, nullptr, 0,
      256, 1.f, 256, 256 * 256, 256, 256);
  gemm_kernel<2, false><<<dim3(2, B_ROWS / 128, 8), 256, 0, stream>>>(
      xconv_b, HDIM, WkT, 256, bk, nullptr, k_b, HDIM, nullptr, 0,
      256, 0.0625f, 256, 256 * 256, 256, 256);
  gemm_kernel<2, false><<<dim3(2, B_ROWS / 128, 8), 256, 0, stream>>>(
      xupl_b, HDIM, WvT, 256, bv, nullptr, v_b, HDIM, nullptr, 0,
      256, 1.f, 256, 256 * 256, 256, 256);

  // ---- i/f dual GEMM + fused gate -> m_t, c_t, n_t
  ifgate256_kernel<<<dim3(HDIM / 128, B_ROWS / 256, 1), 512, 0, stream>>>(
      xconv_b, WiT, WfT, bi, bf_, m_prev, c_prev, n_prev, v_b, k_b,
      out_m, out_c, out_n);

  // ---- transpose q and n_t to k-major bf16 for the denom GEMM
  wtrans_kernel<<<dim3(HDIM / 64, B_ROWS / 64, 1), 256, 0, stream>>>(q_f, qT_b, B_ROWS, HDIM);
  wtrans_kernel<<<dim3(HDIM / 64, B_ROWS / 64, 1), 256, 0, stream>>>(out_n, nT_b, B_ROWS, HDIM);

  // ---- denom: split-K(4) GEMM partials + reduce
  gemm256_kernel<0, false><<<dim3(HDIM / 256, HDIM / 256, 4), 512, 0, stream>>>(
      nT_b, B_ROWS, qT_b, B_ROWS, nullptr, part, nullptr, HDIM, nullptr, 0,
      2048, 1.f, 2048, 2048, (long long)HDIM * HDIM);
  denom_reduce_kernel<<<HDIM, 256, 0, stream>>>(part, dmaxf);

  // ---- h_t + groupnorm + skip + silu gate
  hgn_kernel<<<B_ROWS, 256, 0, stream>>>(o_b, q_f, out_c, dmaxf, xskip_b,
                                         xupr_b, gn_g, gn_b, out_h, act_b);

  // ---- down projection + residual
  gemm256_kernel<0, true><<<dim3(DMODEL / 256, B_ROWS / 256, 1), 512, 0, stream>>>(
      act_b, HDIM, WdownT, HDIM, bdown, out_final, nullptr, DMODEL, x, DMODEL,
      HDIM, 1.f, 0, 0, 0);
}